// Round 5
// baseline (156.650 us; speedup 1.0000x reference)
//
#include <hip/hip_runtime.h>
#include <hip/hip_bf16.h>

typedef __attribute__((ext_vector_type(4))) float  f32x4;
typedef __attribute__((ext_vector_type(8))) __bf16 bf16x8;
typedef __attribute__((ext_vector_type(4))) __bf16 bf16x4;
typedef unsigned int uint_t;

#define S_LEN   4096
#define D_DIM   64
#define NTILE16 256
#define WPB     8     /* waves per block (kv-split factor) */
#define FSTRIDE 1056  /* floats of LDS per wave for the combine */

// ---------------- pre-pass: f32 -> bf16 (Q scaled), V transposed ----------------
__global__ __launch_bounds__(256) void prep_kernel(
    const float* __restrict__ Qg, const float* __restrict__ Kg,
    const float* __restrict__ Vg,
    __bf16* __restrict__ Qbf, __bf16* __restrict__ Kbf, __bf16* __restrict__ Vt)
{
    __shared__ __bf16 vt_l[64][72];

    const float SCALE = 0.125f * 1.44269504088896340736f; // 1/sqrt(64) * log2(e)
    const int tid   = threadIdx.x;
    const int bid   = blockIdx.x;
    const int batch = bid >> 6;
    const int s0    = (bid & 63) << 6;
    const size_t boff = (size_t)batch * S_LEN * D_DIM;

    const float4* Qp = (const float4*)(Qg + boff + (size_t)s0 * D_DIM);
    const float4* Kp = (const float4*)(Kg + boff + (size_t)s0 * D_DIM);
    const float4* Vp = (const float4*)(Vg + boff + (size_t)s0 * D_DIM);
    bf16x4* Qo = (bf16x4*)(Qbf + boff + (size_t)s0 * D_DIM);
    bf16x4* Ko = (bf16x4*)(Kbf + boff + (size_t)s0 * D_DIM);

    #pragma unroll
    for (int c = 0; c < 4; ++c) {
        const int e = c * 256 + tid;          // 1024 float4s in the 64x64 tile
        float4 q4 = Qp[e];
        float4 k4 = Kp[e];
        float4 v4 = Vp[e];
        bf16x4 qo, ko;
        qo[0] = (__bf16)(q4.x * SCALE); qo[1] = (__bf16)(q4.y * SCALE);
        qo[2] = (__bf16)(q4.z * SCALE); qo[3] = (__bf16)(q4.w * SCALE);
        ko[0] = (__bf16)k4.x; ko[1] = (__bf16)k4.y;
        ko[2] = (__bf16)k4.z; ko[3] = (__bf16)k4.w;
        Qo[e] = qo; Ko[e] = ko;
        const int s = e >> 4;
        const int d = (e & 15) * 4;
        vt_l[d + 0][s] = (__bf16)v4.x;
        vt_l[d + 1][s] = (__bf16)v4.y;
        vt_l[d + 2][s] = (__bf16)v4.z;
        vt_l[d + 3][s] = (__bf16)v4.w;
    }
    __syncthreads();

    const int d  = tid >> 2;
    const int sq = tid & 3;
    __bf16* vo = Vt + (size_t)batch * D_DIM * S_LEN + (size_t)d * S_LEN + s0 + sq * 16;
    *(bf16x8*)vo       = *(const bf16x8*)&vt_l[d][sq * 16];
    *(bf16x8*)(vo + 8) = *(const bf16x8*)&vt_l[d][sq * 16 + 8];
}

// ---------------- main: kv-split, register-dataflow causal FA ----------------
__global__ __launch_bounds__(512, 8) void fattn_kernel(
    const __bf16* __restrict__ Qbf, const __bf16* __restrict__ Kbf,
    const __bf16* __restrict__ Vt, float* __restrict__ Og)
{
    __shared__ __align__(16) float smem_f[WPB * FSTRIDE];   // 33792 B

    const int tid  = threadIdx.x;
    const int w    = tid >> 6;
    const int lane = tid & 63;
    const int g    = lane >> 4;   // 4 groups of 16 lanes
    const int ln   = lane & 15;
    const bool oddg = (g & 1);

    float* F = smem_f + w * FSTRIDE;

    // ---- sum-balanced tile permutation: any 4 blocks at stride 256 sum to 510 ----
    const int bid   = blockIdx.x;
    const int batch = bid & 3;
    const int c     = bid >> 2;          // 0..255
    const int cp    = c & 63;
    const int s     = c >> 6;
    int tile16;
    if      (s == 0) tile16 = 255 - cp;  // longest first (LPT)
    else if (s == 1) tile16 = cp;
    else if (s == 2) tile16 = 191 - cp;
    else             tile16 = 64 + cp;

    const int q0   = tile16 << 4;
    const int nkvt = (q0 + 16 + 63) >> 6;

    const size_t boff = (size_t)batch * S_LEN * D_DIM;
    const __bf16* Qb = Qbf + boff;
    const __bf16* Kb = Kbf + boff;
    const __bf16* Vb = Vt  + boff;       // [64][4096] rows of d
    float*        Ob = Og  + boff;

    // Q fragments (B-operand: n=ln -> q, k = ds*32+g*8+i)
    bf16x8 qf[2];
    #pragma unroll
    for (int ds = 0; ds < 2; ++ds)
        qf[ds] = *(const bf16x8*)&Qb[(size_t)(q0 + ln) * D_DIM + ds * 32 + g * 8];

    f32x4 acco[4];
    #pragma unroll
    for (int nb = 0; nb < 4; ++nb) {
        acco[nb][0] = 0.f; acco[nb][1] = 0.f; acco[nb][2] = 0.f; acco[nb][3] = 0.f;
    }
    float mrun = -1e30f, lrun = 0.f;     // per-lane: q-row = q0 + ln (l is g-partial)

    for (int t = w; t < nkvt; t += WPB) {
        const int kv0 = t << 6;

        // ---- K fragments (A-operand: m=ln -> kv) ----
        bf16x8 kf[4][2];
        #pragma unroll
        for (int ns = 0; ns < 4; ++ns) {
            const __bf16* kp = Kb + (size_t)(kv0 + ns * 16 + ln) * D_DIM + g * 8;
            kf[ns][0] = *(const bf16x8*)kp;
            kf[ns][1] = *(const bf16x8*)(kp + 32);
        }
        // ---- V fragments (B-operand for PV), issued early ----
        bf16x8 vf[4][2];
        #pragma unroll
        for (int nb = 0; nb < 4; ++nb) {
            const __bf16* vp = Vb + (size_t)(nb * 16 + ln) * S_LEN + kv0 + g * 8;
            vf[nb][0] = *(const bf16x8*)vp;
            vf[nb][1] = *(const bf16x8*)(vp + 32);
        }

        // ---- swapped QK^T: accs = S^T[kv][q]; lane holds q=ln, kv=ns*16+g*4+i ----
        f32x4 accs[4];
        #pragma unroll
        for (int ns = 0; ns < 4; ++ns) {
            accs[ns][0] = 0.f; accs[ns][1] = 0.f; accs[ns][2] = 0.f; accs[ns][3] = 0.f;
            accs[ns] = __builtin_amdgcn_mfma_f32_16x16x32_bf16(kf[ns][0], qf[0], accs[ns], 0, 0, 0);
            accs[ns] = __builtin_amdgcn_mfma_f32_16x16x32_bf16(kf[ns][1], qf[1], accs[ns], 0, 0, 0);
        }

        // ---- causal mask (diagonal kv-tile only) ----
        if (t == nkvt - 1) {
            const int qg = q0 + ln;
            #pragma unroll
            for (int ns = 0; ns < 4; ++ns)
                #pragma unroll
                for (int i = 0; i < 4; ++i)
                    if (kv0 + ns * 16 + g * 4 + i > qg) accs[ns][i] = -1e30f;
        }

        // ---- lane-local online softmax; cross-g reduce only for the MAX ----
        float mx = accs[0][0];
        #pragma unroll
        for (int ns = 0; ns < 4; ++ns)
            #pragma unroll
            for (int i = 0; i < 4; ++i) mx = fmaxf(mx, accs[ns][i]);
        mx = fmaxf(mx, __shfl_xor(mx, 16));
        mx = fmaxf(mx, __shfl_xor(mx, 32));
        const float mnew  = fmaxf(mrun, mx);
        const float alpha = exp2f(mrun - mnew);
        mrun = mnew;
        float rs = 0.f;
        #pragma unroll
        for (int ns = 0; ns < 4; ++ns)
            #pragma unroll
            for (int i = 0; i < 4; ++i) {
                accs[ns][i] = exp2f(accs[ns][i] - mnew);
                rs += accs[ns][i];
            }
        lrun = lrun * alpha + rs;   // g-partial; combined across g at epilogue

        // ---- broadcast alpha to acco row layout (row = g*4+i) and rescale ----
        float ar[4];
        #pragma unroll
        for (int i = 0; i < 4; ++i)
            ar[i] = __shfl(alpha, (g << 4) + (g << 2) + i);
        #pragma unroll
        for (int nb = 0; nb < 4; ++nb)
            #pragma unroll
            for (int i = 0; i < 4; ++i) acco[nb][i] *= ar[i];

        // ---- P^T -> A-fragment transpose, fully in registers ----
        uint_t cpk[4][2];
        #pragma unroll
        for (int ns = 0; ns < 4; ++ns)
            #pragma unroll
            for (int jp = 0; jp < 2; ++jp) {
                float lo = accs[ns][2 * jp], hi = accs[ns][2 * jp + 1];
                asm("v_cvt_pk_bf16_f32 %0, %1, %2" : "=v"(cpk[ns][jp]) : "v"(lo), "v"(hi));
            }
        union { uint_t u[4]; bf16x8 v; } pfu[2];
        #pragma unroll
        for (int ks = 0; ks < 2; ++ks)
            #pragma unroll
            for (int jp = 0; jp < 2; ++jp) {
                uint_t a = cpk[2 * ks][jp], b = cpk[2 * ks + 1][jp];
                asm volatile("v_permlane32_swap_b32 %0, %1" : "+v"(a), "+v"(b));
                const uint_t rax = (uint_t)__shfl_xor((int)a, 16);
                const uint_t rbx = (uint_t)__shfl_xor((int)b, 16);
                pfu[ks].u[jp]     = oddg ? rbx : a;    // k = g*8 + 2jp
                pfu[ks].u[2 + jp] = oddg ? b   : rax;  // k = g*8 + 4 + 2jp
            }

        // ---- PV : O += P @ V ----
        #pragma unroll
        for (int nb = 0; nb < 4; ++nb) {
            acco[nb] = __builtin_amdgcn_mfma_f32_16x16x32_bf16(pfu[0].v, vf[nb][0], acco[nb], 0, 0, 0);
            acco[nb] = __builtin_amdgcn_mfma_f32_16x16x32_bf16(pfu[1].v, vf[nb][1], acco[nb], 0, 0, 0);
        }
    }

    // ---- cross-g combine of the deferred l-partials (once) ----
    lrun += __shfl_xor(lrun, 16);
    lrun += __shfl_xor(lrun, 32);

    // ---- partial write: per-row m, l via shuffle; O already row-indexed ----
    float mr[4], lr[4];
    #pragma unroll
    for (int i = 0; i < 4; ++i) {
        const int srcl = (g << 4) + (g << 2) + i;
        mr[i] = __shfl(mrun, srcl);
        lr[i] = __shfl(lrun, srcl);
    }
    if (ln == 0) {
        #pragma unroll
        for (int i = 0; i < 4; ++i) {
            F[g * 4 + i]      = mr[i];
            F[16 + g * 4 + i] = lr[i];
        }
    }
    #pragma unroll
    for (int nb = 0; nb < 4; ++nb)
        #pragma unroll
        for (int i = 0; i < 4; ++i)
            F[32 + (g * 4 + i) * 64 + nb * 16 + ln] = acco[nb][i];

    __syncthreads();

    // ---- combine 8 partials: 512 threads cover 16 rows x 64 dims, 2 each ----
    #pragma unroll
    for (int rep = 0; rep < 2; ++rep) {
        const int o = tid + rep * 512;
        const int r = o >> 6;
        const int d = o & 63;

        float M = -1e30f;
        #pragma unroll
        for (int w2 = 0; w2 < WPB; ++w2)
            M = fmaxf(M, smem_f[w2 * FSTRIDE + r]);

        float L = 0.f, val = 0.f;
        #pragma unroll
        for (int w2 = 0; w2 < WPB; ++w2) {
            const float* F2 = smem_f + w2 * FSTRIDE;
            const float al = exp2f(F2[r] - M);
            L   += F2[16 + r] * al;
            val += F2[32 + r * 64 + d] * al;
        }
        Ob[(size_t)(q0 + r) * D_DIM + d] = val / L;
    }
}

extern "C" void kernel_launch(void* const* d_in, const int* in_sizes, int n_in,
                              void* d_out, int out_size, void* d_ws, size_t ws_size,
                              hipStream_t stream) {
    const float* q = (const float*)d_in[0];
    const float* k = (const float*)d_in[1];
    const float* v = (const float*)d_in[2];
    float* o = (float*)d_out;

    __bf16* Qbf = (__bf16*)d_ws;                       // 2 MB
    __bf16* Kbf = Qbf + (size_t)4 * S_LEN * D_DIM;     // 2 MB
    __bf16* Vt  = Kbf + (size_t)4 * S_LEN * D_DIM;     // 2 MB (transposed [b][d][s])

    hipLaunchKernelGGL(prep_kernel, dim3(256), dim3(256), 0, stream, q, k, v, Qbf, Kbf, Vt);
    // 1024 blocks = 4 batches x 256 q-tiles (sum-balanced permutation), 8 waves kv-split
    hipLaunchKernelGGL(fattn_kernel, dim3(1024), dim3(512), 0, stream, Qbf, Kbf, Vt, o);
}

// Round 6
// 79.546 us; speedup vs baseline: 1.9693x; 1.9693x over previous
//
#include <hip/hip_runtime.h>
#include <hip/hip_bf16.h>

typedef __attribute__((ext_vector_type(4))) float  f32x4;
typedef __attribute__((ext_vector_type(8))) __bf16 bf16x8;
typedef __attribute__((ext_vector_type(4))) __bf16 bf16x4;
typedef unsigned int uint_t;

#define S_LEN   4096
#define D_DIM   64
#define NTILE16 256
#define WPB     8     /* waves per block (kv-split factor) */
#define FSTRIDE 1056  /* floats of LDS per wave for the combine */

// ---------------- pre-pass: f32 -> bf16 (Q scaled), V transposed ----------------
__global__ __launch_bounds__(256) void prep_kernel(
    const float* __restrict__ Qg, const float* __restrict__ Kg,
    const float* __restrict__ Vg,
    __bf16* __restrict__ Qbf, __bf16* __restrict__ Kbf, __bf16* __restrict__ Vt)
{
    __shared__ __bf16 vt_l[64][72];

    const float SCALE = 0.125f * 1.44269504088896340736f; // 1/sqrt(64) * log2(e)
    const int tid   = threadIdx.x;
    const int bid   = blockIdx.x;
    const int batch = bid >> 6;
    const int s0    = (bid & 63) << 6;
    const size_t boff = (size_t)batch * S_LEN * D_DIM;

    const float4* Qp = (const float4*)(Qg + boff + (size_t)s0 * D_DIM);
    const float4* Kp = (const float4*)(Kg + boff + (size_t)s0 * D_DIM);
    const float4* Vp = (const float4*)(Vg + boff + (size_t)s0 * D_DIM);
    bf16x4* Qo = (bf16x4*)(Qbf + boff + (size_t)s0 * D_DIM);
    bf16x4* Ko = (bf16x4*)(Kbf + boff + (size_t)s0 * D_DIM);

    #pragma unroll
    for (int c = 0; c < 4; ++c) {
        const int e = c * 256 + tid;          // 1024 float4s in the 64x64 tile
        float4 q4 = Qp[e];
        float4 k4 = Kp[e];
        float4 v4 = Vp[e];
        bf16x4 qo, ko;
        qo[0] = (__bf16)(q4.x * SCALE); qo[1] = (__bf16)(q4.y * SCALE);
        qo[2] = (__bf16)(q4.z * SCALE); qo[3] = (__bf16)(q4.w * SCALE);
        ko[0] = (__bf16)k4.x; ko[1] = (__bf16)k4.y;
        ko[2] = (__bf16)k4.z; ko[3] = (__bf16)k4.w;
        Qo[e] = qo; Ko[e] = ko;
        const int s = e >> 4;
        const int d = (e & 15) * 4;
        vt_l[d + 0][s] = (__bf16)v4.x;
        vt_l[d + 1][s] = (__bf16)v4.y;
        vt_l[d + 2][s] = (__bf16)v4.z;
        vt_l[d + 3][s] = (__bf16)v4.w;
    }
    __syncthreads();

    const int d  = tid >> 2;
    const int sq = tid & 3;
    __bf16* vo = Vt + (size_t)batch * D_DIM * S_LEN + (size_t)d * S_LEN + s0 + sq * 16;
    *(bf16x8*)vo       = *(const bf16x8*)&vt_l[d][sq * 16];
    *(bf16x8*)(vo + 8) = *(const bf16x8*)&vt_l[d][sq * 16 + 8];
}

// ---------------- main: kv-split, register-dataflow causal FA ----------------
__global__ __launch_bounds__(512, 4) void fattn_kernel(
    const __bf16* __restrict__ Qbf, const __bf16* __restrict__ Kbf,
    const __bf16* __restrict__ Vt, float* __restrict__ Og)
{
    __shared__ __align__(16) float smem_f[WPB * FSTRIDE];   // 33792 B

    const int tid  = threadIdx.x;
    const int w    = tid >> 6;
    const int lane = tid & 63;
    const int g    = lane >> 4;   // 4 groups of 16 lanes
    const int ln   = lane & 15;
    const bool oddg = (g & 1);

    float* F = smem_f + w * FSTRIDE;

    // ---- sum-balanced tile permutation: any 4 blocks at stride 256 sum to 510 ----
    const int bid   = blockIdx.x;
    const int batch = bid & 3;
    const int c     = bid >> 2;          // 0..255
    const int cp    = c & 63;
    const int s     = c >> 6;
    int tile16;
    if      (s == 0) tile16 = 255 - cp;  // longest first (LPT)
    else if (s == 1) tile16 = cp;
    else if (s == 2) tile16 = 191 - cp;
    else             tile16 = 64 + cp;

    const int q0   = tile16 << 4;
    const int nkvt = (q0 + 16 + 63) >> 6;

    const size_t boff = (size_t)batch * S_LEN * D_DIM;
    const __bf16* Qb = Qbf + boff;
    const __bf16* Kb = Kbf + boff;
    const __bf16* Vb = Vt  + boff;       // [64][4096] rows of d
    float*        Ob = Og  + boff;

    // Q fragments (B-operand: n=ln -> q, k = ds*32+g*8+i)
    bf16x8 qf[2];
    #pragma unroll
    for (int ds = 0; ds < 2; ++ds)
        qf[ds] = *(const bf16x8*)&Qb[(size_t)(q0 + ln) * D_DIM + ds * 32 + g * 8];

    f32x4 acco[4];
    #pragma unroll
    for (int nb = 0; nb < 4; ++nb) {
        acco[nb][0] = 0.f; acco[nb][1] = 0.f; acco[nb][2] = 0.f; acco[nb][3] = 0.f;
    }
    float mrun = -1e30f, lrun = 0.f;     // per-lane: q-row = q0 + ln (l is g-partial)

    for (int t = w; t < nkvt; t += WPB) {
        const int kv0 = t << 6;

        // ---- K fragments (A-operand: m=ln -> kv) ----
        bf16x8 kf[4][2];
        #pragma unroll
        for (int ns = 0; ns < 4; ++ns) {
            const __bf16* kp = Kb + (size_t)(kv0 + ns * 16 + ln) * D_DIM + g * 8;
            kf[ns][0] = *(const bf16x8*)kp;
            kf[ns][1] = *(const bf16x8*)(kp + 32);
        }
        // ---- V fragments (B-operand for PV), issued early ----
        bf16x8 vf[4][2];
        #pragma unroll
        for (int nb = 0; nb < 4; ++nb) {
            const __bf16* vp = Vb + (size_t)(nb * 16 + ln) * S_LEN + kv0 + g * 8;
            vf[nb][0] = *(const bf16x8*)vp;
            vf[nb][1] = *(const bf16x8*)(vp + 32);
        }

        // ---- swapped QK^T: accs = S^T[kv][q]; lane holds q=ln, kv=ns*16+g*4+i ----
        f32x4 accs[4];
        #pragma unroll
        for (int ns = 0; ns < 4; ++ns) {
            accs[ns][0] = 0.f; accs[ns][1] = 0.f; accs[ns][2] = 0.f; accs[ns][3] = 0.f;
            accs[ns] = __builtin_amdgcn_mfma_f32_16x16x32_bf16(kf[ns][0], qf[0], accs[ns], 0, 0, 0);
            accs[ns] = __builtin_amdgcn_mfma_f32_16x16x32_bf16(kf[ns][1], qf[1], accs[ns], 0, 0, 0);
        }

        // ---- causal mask (diagonal kv-tile only) ----
        if (t == nkvt - 1) {
            const int qg = q0 + ln;
            #pragma unroll
            for (int ns = 0; ns < 4; ++ns)
                #pragma unroll
                for (int i = 0; i < 4; ++i)
                    if (kv0 + ns * 16 + g * 4 + i > qg) accs[ns][i] = -1e30f;
        }

        // ---- lane-local online softmax; cross-g reduce only for the MAX ----
        float mx = accs[0][0];
        #pragma unroll
        for (int ns = 0; ns < 4; ++ns)
            #pragma unroll
            for (int i = 0; i < 4; ++i) mx = fmaxf(mx, accs[ns][i]);
        mx = fmaxf(mx, __shfl_xor(mx, 16));
        mx = fmaxf(mx, __shfl_xor(mx, 32));
        const float mnew  = fmaxf(mrun, mx);
        const float alpha = exp2f(mrun - mnew);
        mrun = mnew;
        float rs = 0.f;
        #pragma unroll
        for (int ns = 0; ns < 4; ++ns)
            #pragma unroll
            for (int i = 0; i < 4; ++i) {
                accs[ns][i] = exp2f(accs[ns][i] - mnew);
                rs += accs[ns][i];
            }
        lrun = lrun * alpha + rs;   // g-partial; combined across g at epilogue

        // ---- broadcast alpha to acco row layout (row = g*4+i) and rescale ----
        float ar[4];
        #pragma unroll
        for (int i = 0; i < 4; ++i)
            ar[i] = __shfl(alpha, (g << 4) + (g << 2) + i);
        #pragma unroll
        for (int nb = 0; nb < 4; ++nb)
            #pragma unroll
            for (int i = 0; i < 4; ++i) acco[nb][i] *= ar[i];

        // ---- P^T -> A-fragment transpose, fully in registers ----
        uint_t cpk[4][2];
        #pragma unroll
        for (int ns = 0; ns < 4; ++ns)
            #pragma unroll
            for (int jp = 0; jp < 2; ++jp) {
                float lo = accs[ns][2 * jp], hi = accs[ns][2 * jp + 1];
                asm("v_cvt_pk_bf16_f32 %0, %1, %2" : "=v"(cpk[ns][jp]) : "v"(lo), "v"(hi));
            }
        union { uint_t u[4]; bf16x8 v; } pfu[2];
        #pragma unroll
        for (int ks = 0; ks < 2; ++ks)
            #pragma unroll
            for (int jp = 0; jp < 2; ++jp) {
                uint_t a = cpk[2 * ks][jp], b = cpk[2 * ks + 1][jp];
                asm volatile("v_permlane32_swap_b32 %0, %1" : "+v"(a), "+v"(b));
                const uint_t rax = (uint_t)__shfl_xor((int)a, 16);
                const uint_t rbx = (uint_t)__shfl_xor((int)b, 16);
                pfu[ks].u[jp]     = oddg ? rbx : a;    // k = g*8 + 2jp
                pfu[ks].u[2 + jp] = oddg ? b   : rax;  // k = g*8 + 4 + 2jp
            }

        // ---- PV : O += P @ V ----
        #pragma unroll
        for (int nb = 0; nb < 4; ++nb) {
            acco[nb] = __builtin_amdgcn_mfma_f32_16x16x32_bf16(pfu[0].v, vf[nb][0], acco[nb], 0, 0, 0);
            acco[nb] = __builtin_amdgcn_mfma_f32_16x16x32_bf16(pfu[1].v, vf[nb][1], acco[nb], 0, 0, 0);
        }
    }

    // ---- cross-g combine of the deferred l-partials (once) ----
    lrun += __shfl_xor(lrun, 16);
    lrun += __shfl_xor(lrun, 32);

    // ---- partial write: per-row m, l via shuffle; O already row-indexed ----
    float mr[4], lr[4];
    #pragma unroll
    for (int i = 0; i < 4; ++i) {
        const int srcl = (g << 4) + (g << 2) + i;
        mr[i] = __shfl(mrun, srcl);
        lr[i] = __shfl(lrun, srcl);
    }
    if (ln == 0) {
        #pragma unroll
        for (int i = 0; i < 4; ++i) {
            F[g * 4 + i]      = mr[i];
            F[16 + g * 4 + i] = lr[i];
        }
    }
    #pragma unroll
    for (int nb = 0; nb < 4; ++nb)
        #pragma unroll
        for (int i = 0; i < 4; ++i)
            F[32 + (g * 4 + i) * 64 + nb * 16 + ln] = acco[nb][i];

    __syncthreads();

    // ---- combine 8 partials: 512 threads cover 16 rows x 64 dims, 2 each ----
    #pragma unroll
    for (int rep = 0; rep < 2; ++rep) {
        const int o = tid + rep * 512;
        const int r = o >> 6;
        const int d = o & 63;

        float M = -1e30f;
        #pragma unroll
        for (int w2 = 0; w2 < WPB; ++w2)
            M = fmaxf(M, smem_f[w2 * FSTRIDE + r]);

        float L = 0.f, val = 0.f;
        #pragma unroll
        for (int w2 = 0; w2 < WPB; ++w2) {
            const float* F2 = smem_f + w2 * FSTRIDE;
            const float al = exp2f(F2[r] - M);
            L   += F2[16 + r] * al;
            val += F2[32 + r * 64 + d] * al;
        }
        Ob[(size_t)(q0 + r) * D_DIM + d] = val / L;
    }
}

extern "C" void kernel_launch(void* const* d_in, const int* in_sizes, int n_in,
                              void* d_out, int out_size, void* d_ws, size_t ws_size,
                              hipStream_t stream) {
    const float* q = (const float*)d_in[0];
    const float* k = (const float*)d_in[1];
    const float* v = (const float*)d_in[2];
    float* o = (float*)d_out;

    __bf16* Qbf = (__bf16*)d_ws;                       // 2 MB
    __bf16* Kbf = Qbf + (size_t)4 * S_LEN * D_DIM;     // 2 MB
    __bf16* Vt  = Kbf + (size_t)4 * S_LEN * D_DIM;     // 2 MB (transposed [b][d][s])

    hipLaunchKernelGGL(prep_kernel, dim3(256), dim3(256), 0, stream, q, k, v, Qbf, Kbf, Vt);
    // 1024 blocks = 4 batches x 256 q-tiles (sum-balanced permutation), 8 waves kv-split
    hipLaunchKernelGGL(fattn_kernel, dim3(1024), dim3(512), 0, stream, Qbf, Kbf, Vt, o);
}